// Round 5
// baseline (935.809 us; speedup 1.0000x reference)
//
#include <hip/hip_runtime.h>
#include <hip/hip_cooperative_groups.h>

namespace cg = cooperative_groups;

typedef __bf16 bf16_t;
typedef __bf16 bf16x4 __attribute__((ext_vector_type(4)));
typedef __bf16 bf16x8 __attribute__((ext_vector_type(8)));
typedef float floatx4 __attribute__((ext_vector_type(4)));

static constexpr int NN  = 8192;
static constexpr int FIN = 512;
static constexpr int NH1 = 256;
static constexpr int NH2 = 128;
static constexpr int NE  = 262144;

// output layout (floats): h1, adj_rec, mu, logvar, z
static constexpr size_t OFF_H1     = 0;
static constexpr size_t OFF_ADJ    = (size_t)NN * NH1;
static constexpr size_t OFF_MU     = OFF_ADJ + (size_t)NN * NN;
static constexpr size_t OFF_LOGVAR = OFF_MU + (size_t)NN * NH2;
static constexpr size_t OFF_Z      = OFF_LOGVAR + (size_t)NN * NH2;

// ---------------- SPMM helper: one wave computes one row (d=256) ----------------
template <bool RELU>
__device__ __forceinline__ void spmm_row(
    int r, const int* __restrict__ row_ptr, const uint2* __restrict__ pw,
    const bf16_t* __restrict__ src, float* __restrict__ dst_f,
    bf16_t* __restrict__ dst_b, int lane) {
  const int li = lane & 15;  // channel group [li*16, li*16+16)
  const int g  = lane >> 4;  // edge slot 0..3
  const int beg = row_ptr[r], end = row_ptr[r + 1];
  float acc[16];
#pragma unroll
  for (int c = 0; c < 16; ++c) acc[c] = 0.f;
  for (int base = beg; base < end; base += 64) {
    const int t = base + lane;
    uint2 cw;
    cw.x = 0; cw.y = 0;
    if (t < end) cw = pw[t];
    const int cnt = min(64, end - base);
    for (int j4 = 0; j4 < cnt; j4 += 4) {
      const int cj = __shfl((int)cw.x, j4 + g);
      const float wj = __shfl(__uint_as_float(cw.y), j4 + g);
      const bf16_t* p = src + (size_t)cj * NH1 + li * 16;
      const bf16x8 v0 = *(const bf16x8*)p;
      const bf16x8 v1 = *(const bf16x8*)(p + 8);
#pragma unroll
      for (int c = 0; c < 8; ++c) {
        acc[c]     += wj * (float)v0[c];
        acc[8 + c] += wj * (float)v1[c];
      }
    }
  }
#pragma unroll
  for (int c = 0; c < 16; ++c) {
    acc[c] += __shfl_xor(acc[c], 16);
    acc[c] += __shfl_xor(acc[c], 32);
    if constexpr (RELU) acc[c] = fmaxf(acc[c], 0.f);
  }
  // static-index extraction of this lane's 4 channels (avoid scratch, rule #20)
  float o0, o1, o2, o3;
  switch (g) {
    case 0: o0 = acc[0];  o1 = acc[1];  o2 = acc[2];  o3 = acc[3];  break;
    case 1: o0 = acc[4];  o1 = acc[5];  o2 = acc[6];  o3 = acc[7];  break;
    case 2: o0 = acc[8];  o1 = acc[9];  o2 = acc[10]; o3 = acc[11]; break;
    default: o0 = acc[12]; o1 = acc[13]; o2 = acc[14]; o3 = acc[15]; break;
  }
  const int ch = li * 16 + g * 4;
  if (dst_f) {
    floatx4 o = (floatx4){o0, o1, o2, o3};
    __builtin_nontemporal_store(o, (floatx4*)(dst_f + (size_t)r * NH1 + ch));
  }
  if (dst_b) {
    bf16x4 o;
    o[0] = (bf16_t)o0; o[1] = (bf16_t)o1; o[2] = (bf16_t)o2; o[3] = (bf16_t)o3;
    *(bf16x4*)(dst_b + (size_t)r * NH1 + ch) = o;
  }
}

// ---------------- the whole VGAE forward as one cooperative kernel ----------------
__global__ __launch_bounds__(256, 4) void vgae_mega(
    const float* __restrict__ x, const float* __restrict__ W1,
    const float* __restrict__ W2, const float* __restrict__ W3,
    const float* __restrict__ edge_w, const int* __restrict__ row,
    const int* __restrict__ col, float* __restrict__ out,
    char* __restrict__ ws) {
  // workspace layout
  bf16_t* XWb  = (bf16_t*)(ws);                             // 4 MB [8192][256]
  bf16_t* h1b  = (bf16_t*)(ws + (4u << 20));                // 4 MB
  bf16_t* gb   = (bf16_t*)(ws + (8u << 20));                // 4 MB
  bf16_t* zbf  = (bf16_t*)(ws + (12u << 20));               // 2 MB [8192][128]
  bf16_t* W1T  = (bf16_t*)(ws + (14u << 20));               // 256 KB
  bf16_t* W23T = (bf16_t*)(ws + (14u << 20) + (1u << 19));  // 128 KB
  int* counts   = (int*)(ws + (15u << 20));
  int* cursor   = counts + NN;
  int* row_ptr  = cursor + NN;                               // NN+1
  uint2* pw     = (uint2*)(ws + (15u << 20) + (1u << 18));   // 2 MB

  cg::grid_group grid = cg::this_grid();
  const int tid  = threadIdx.x;
  const int bid  = blockIdx.x;
  const int nblk = gridDim.x;
  const int ntot = nblk * 256;
  const int gid  = bid * 256 + tid;
  const int lane = tid & 63;
  const int wid  = tid >> 6;
  const int l15  = lane & 15;
  const int lg   = lane >> 4;

  __shared__ float smem[4 * 16 * 68];  // 17408 B: adj transpose / scan scratch

  // ---- P0: zero counts + cursor ----
  for (int i = gid; i < 2 * NN; i += ntot) counts[i] = 0;
  grid.sync();

  // ---- P1: histogram of row ----
  for (int e = gid; e < NE; e += ntot) atomicAdd(&counts[row[e]], 1);
  grid.sync();

  // ---- P2: scan (block 0) || weight transpose+bf16 (other blocks) ----
  if (bid == 0) {
    int* part = (int*)smem;
    int v[32];
    int run = 0;
#pragma unroll
    for (int j = 0; j < 32; ++j) { run += counts[tid * 32 + j]; v[j] = run; }
    part[tid] = run;
    __syncthreads();
    for (int off = 1; off < 256; off <<= 1) {
      const int xv = (tid >= off) ? part[tid - off] : 0;
      __syncthreads();
      part[tid] += xv;
      __syncthreads();
    }
    const int base = tid ? part[tid - 1] : 0;
    if (tid == 0) row_ptr[0] = 0;
#pragma unroll
    for (int j = 0; j < 32; ++j) row_ptr[tid * 32 + j + 1] = base + v[j];
  } else {
    for (int i = (bid - 1) * 256 + tid; i < NH1 * FIN + NH1 * NH1;
         i += (nblk - 1) * 256) {
      if (i < NH1 * FIN) {
        const int n = i >> 9, k = i & 511;
        W1T[i] = (bf16_t)W1[k * NH1 + n];
      } else {
        const int i2 = i - NH1 * FIN;
        const int n = i2 >> 8, k = i2 & 255;
        W23T[i2] = (bf16_t)(n < NH2 ? W2[k * NH2 + n] : W3[k * NH2 + (n - NH2)]);
      }
    }
  }
  grid.sync();

  // ---- P3: fill packed (col, w) in CSR order ----
  for (int e = gid; e < NE; e += ntot) {
    const int r = row[e];
    const int p = atomicAdd(&cursor[r], 1);
    uint2 v;
    v.x = (unsigned)col[e];
    v.y = __float_as_uint(edge_w[e]);
    pw[row_ptr[r] + p] = v;
  }
  grid.sync();

  // ---- P4: XWb = bf16(x @ W1), 1024 tiles of 32x64, wave = 16x32 ----
  for (int t = bid; t < 1024; t += nblk) {
    const int rbase = (t >> 2) * 32 + (wid >> 1) * 16;
    const int cbase = (t & 3) * 64 + (wid & 1) * 32;
    floatx4 acc0 = (floatx4){0.f, 0.f, 0.f, 0.f};
    floatx4 acc1 = (floatx4){0.f, 0.f, 0.f, 0.f};
#pragma unroll 1
    for (int kk = 0; kk < FIN; kk += 32) {
      const float* p = x + (size_t)(rbase + l15) * FIN + kk + lg * 8;
      const floatx4 lo = *(const floatx4*)p;
      const floatx4 hi = *(const floatx4*)(p + 4);
      bf16x8 af;
      af[0] = (bf16_t)lo[0]; af[1] = (bf16_t)lo[1];
      af[2] = (bf16_t)lo[2]; af[3] = (bf16_t)lo[3];
      af[4] = (bf16_t)hi[0]; af[5] = (bf16_t)hi[1];
      af[6] = (bf16_t)hi[2]; af[7] = (bf16_t)hi[3];
      const bf16x8 b0 =
          *(const bf16x8*)(W1T + (size_t)(cbase + l15) * FIN + kk + lg * 8);
      const bf16x8 b1 =
          *(const bf16x8*)(W1T + (size_t)(cbase + 16 + l15) * FIN + kk + lg * 8);
      acc0 = __builtin_amdgcn_mfma_f32_16x16x32_bf16(af, b0, acc0, 0, 0, 0);
      acc1 = __builtin_amdgcn_mfma_f32_16x16x32_bf16(af, b1, acc1, 0, 0, 0);
    }
#pragma unroll
    for (int r = 0; r < 4; ++r) {
      XWb[(size_t)(rbase + lg * 4 + r) * NH1 + cbase + l15] = (bf16_t)acc0[r];
      XWb[(size_t)(rbase + lg * 4 + r) * NH1 + cbase + 16 + l15] = (bf16_t)acc1[r];
    }
  }
  grid.sync();

  // ---- P5: h1 = relu(A . XWb) -> out f32 (nt) + h1b bf16 ----
  const int gwv = bid * 4 + wid;
  const int nwv = nblk * 4;
  for (int r = gwv; r < NN; r += nwv)
    spmm_row<true>(r, row_ptr, pw, XWb, out + OFF_H1, h1b, lane);
  grid.sync();

  // ---- P6: gb = bf16(A . h1b) ----
  for (int r = gwv; r < NN; r += nwv)
    spmm_row<false>(r, row_ptr, pw, h1b, nullptr, gb, lane);
  grid.sync();

  // ---- P7: [mu|logvar] = gb @ [W2|W3]; writes mu/z/logvar f32 + zbf bf16 ----
  for (int t = bid; t < 1024; t += nblk) {
    const int rbase = (t >> 2) * 32 + (wid >> 1) * 16;
    const int cbase = (t & 3) * 64 + (wid & 1) * 32;
    floatx4 acc0 = (floatx4){0.f, 0.f, 0.f, 0.f};
    floatx4 acc1 = (floatx4){0.f, 0.f, 0.f, 0.f};
#pragma unroll 1
    for (int kk = 0; kk < NH1; kk += 32) {
      const bf16x8 af =
          *(const bf16x8*)(gb + (size_t)(rbase + l15) * NH1 + kk + lg * 8);
      const bf16x8 b0 =
          *(const bf16x8*)(W23T + (size_t)(cbase + l15) * NH1 + kk + lg * 8);
      const bf16x8 b1 =
          *(const bf16x8*)(W23T + (size_t)(cbase + 16 + l15) * NH1 + kk + lg * 8);
      acc0 = __builtin_amdgcn_mfma_f32_16x16x32_bf16(af, b0, acc0, 0, 0, 0);
      acc1 = __builtin_amdgcn_mfma_f32_16x16x32_bf16(af, b1, acc1, 0, 0, 0);
    }
#pragma unroll
    for (int ct = 0; ct < 2; ++ct) {
#pragma unroll
      for (int r = 0; r < 4; ++r) {
        const int orow = rbase + lg * 4 + r;
        const int ocol = cbase + ct * 16 + l15;
        const float v = ct ? acc1[r] : acc0[r];
        if (ocol < NH2) {
          out[OFF_MU + (size_t)orow * NH2 + ocol] = v;
          out[OFF_Z + (size_t)orow * NH2 + ocol] = v;
          zbf[(size_t)orow * NH2 + ocol] = (bf16_t)v;
        } else {
          out[OFF_LOGVAR + (size_t)orow * NH2 + (ocol - NH2)] = v;
        }
      }
    }
  }
  grid.sync();

  // ---- P8: adj = z @ z^T, 8192 tiles of 64x128, wave = 32x64 (RT=2,CT=4) ----
  {
    float* Lw = smem + wid * (16 * 68);
    float* Cb = out + OFF_ADJ;
    const int per = (8192 + nblk - 1) / nblk;
    for (int i = 0; i < per; ++i) {
      const int t = bid * per + i;
      if (t >= 8192) break;
      const int rb = (t >> 6) * 64 + (wid >> 1) * 32;
      const int cb = (t & 63) * 128 + (wid & 1) * 64;
      floatx4 acc[2][4];
#pragma unroll
      for (int rt = 0; rt < 2; ++rt)
#pragma unroll
        for (int ct = 0; ct < 4; ++ct) acc[rt][ct] = (floatx4){0.f, 0.f, 0.f, 0.f};
#pragma unroll 1
      for (int kk = 0; kk < NH2; kk += 32) {
        bf16x8 a[2], b[4];
#pragma unroll
        for (int rt = 0; rt < 2; ++rt)
          a[rt] = *(const bf16x8*)(zbf + (size_t)(rb + rt * 16 + l15) * NH2 + kk +
                                   lg * 8);
#pragma unroll
        for (int ct = 0; ct < 4; ++ct)
          b[ct] = *(const bf16x8*)(zbf + (size_t)(cb + ct * 16 + l15) * NH2 + kk +
                                   lg * 8);
#pragma unroll
        for (int rt = 0; rt < 2; ++rt)
#pragma unroll
          for (int ct = 0; ct < 4; ++ct)
            acc[rt][ct] = __builtin_amdgcn_mfma_f32_16x16x32_bf16(
                a[rt], b[ct], acc[rt][ct], 0, 0, 0);
      }
#pragma unroll
      for (int rt = 0; rt < 2; ++rt) {
#pragma unroll
        for (int ct = 0; ct < 4; ++ct)
#pragma unroll
          for (int r = 0; r < 4; ++r)
            Lw[(lg * 4 + r) * 68 + ct * 16 + l15] = acc[rt][ct][r];
        __syncthreads();
#pragma unroll
        for (int it2 = 0; it2 < 4; ++it2) {
          const int u = it2 * 64 + lane;
          const int rr = u >> 4, cq = u & 15;
          const floatx4 v = *(const floatx4*)(Lw + rr * 68 + cq * 4);
          __builtin_nontemporal_store(
              v, (floatx4*)(Cb + (size_t)(rb + rt * 16 + rr) * NN + cb + cq * 4));
        }
        __syncthreads();
      }
    }
  }
}

extern "C" void kernel_launch(void* const* d_in, const int* in_sizes, int n_in,
                              void* d_out, int out_size, void* d_ws, size_t ws_size,
                              hipStream_t stream) {
  const float* x      = (const float*)d_in[0];
  const float* W1     = (const float*)d_in[1];
  const float* W2     = (const float*)d_in[2];
  const float* W3     = (const float*)d_in[3];
  const float* edge_w = (const float*)d_in[4];
  const int*   row    = (const int*)d_in[5];
  const int*   col    = (const int*)d_in[6];
  float* out = (float*)d_out;
  char*  ws  = (char*)d_ws;

  int nb = 0;
  if (hipOccupancyMaxActiveBlocksPerMultiprocessor(&nb, vgae_mega, 256, 0) !=
          hipSuccess ||
      nb < 1)
    nb = 1;
  int grid = nb * 256;  // 256 CUs on MI355X
  if (grid > 1024) grid = 1024;

  void* kargs[] = {(void*)&x,      (void*)&W1,  (void*)&W2,  (void*)&W3,
                   (void*)&edge_w, (void*)&row, (void*)&col, (void*)&out,
                   (void*)&ws};
  hipLaunchCooperativeKernel((const void*)vgae_mega, dim3(grid), dim3(256),
                             kargs, 0, stream);
}

// Round 6
// 158.488 us; speedup vs baseline: 5.9046x; 5.9046x over previous
//
#include <hip/hip_runtime.h>

typedef __bf16 bf16_t;
typedef __bf16 bf16x4 __attribute__((ext_vector_type(4)));
typedef __bf16 bf16x8 __attribute__((ext_vector_type(8)));
typedef float floatx4 __attribute__((ext_vector_type(4)));

static constexpr int NN  = 8192;
static constexpr int FIN = 512;
static constexpr int NH1 = 256;
static constexpr int NH2 = 128;
static constexpr int NE  = 262144;

// output layout (floats): h1, adj_rec, mu, logvar, z
static constexpr size_t OFF_H1     = 0;
static constexpr size_t OFF_ADJ    = (size_t)NN * NH1;
static constexpr size_t OFF_MU     = OFF_ADJ + (size_t)NN * NN;
static constexpr size_t OFF_LOGVAR = OFF_MU + (size_t)NN * NH2;
static constexpr size_t OFF_Z      = OFF_LOGVAR + (size_t)NN * NH2;

// ---------------- fused prep: weight transpose/convert + edge count ----------------
__global__ __launch_bounds__(256) void prep_all(
    const float* __restrict__ W1, const float* __restrict__ W2,
    const float* __restrict__ W3, const int* __restrict__ row,
    bf16_t* __restrict__ W1T, bf16_t* __restrict__ W23T,
    int* __restrict__ counts) {
  const int gid = blockIdx.x * 256 + threadIdx.x;  // grid*256 == NE exactly
  atomicAdd(&counts[row[gid]], 1);
  if (gid < NH1 * FIN) {
    const int n = gid >> 9, k = gid & 511;
    W1T[gid] = (bf16_t)W1[k * NH1 + n];
  }
  if (gid < NH1 * NH1) {
    const int n = gid >> 8, k = gid & 255;
    W23T[gid] = (bf16_t)(n < NH2 ? W2[k * NH2 + n] : W3[k * NH2 + (n - NH2)]);
  }
}

// ---------------- scan of 8192 counts -> row_ptr ----------------
__global__ __launch_bounds__(1024) void scan8k(const int* __restrict__ counts,
                                               int* __restrict__ row_ptr) {
  __shared__ int part[1024];
  const int t = threadIdx.x;
  int v[8];
  int run = 0;
#pragma unroll
  for (int j = 0; j < 8; ++j) { run += counts[t * 8 + j]; v[j] = run; }
  part[t] = run;
  __syncthreads();
  for (int off = 1; off < 1024; off <<= 1) {
    const int x = (t >= off) ? part[t - off] : 0;
    __syncthreads();
    part[t] += x;
    __syncthreads();
  }
  const int base = (t > 0) ? part[t - 1] : 0;
#pragma unroll
  for (int j = 0; j < 8; ++j) row_ptr[t * 8 + j + 1] = base + v[j];
  if (t == 0) row_ptr[0] = 0;
}

// ---------------- edge fill: scatter packed (col, weight) ----------------
__global__ __launch_bounds__(256) void edge_fill(
    const int* __restrict__ row, const int* __restrict__ col,
    const float* __restrict__ edge_w, const int* __restrict__ row_ptr,
    int* __restrict__ cursor, uint2* __restrict__ pw) {
  const int e = blockIdx.x * 256 + threadIdx.x;
  const int r = row[e];
  const int p = atomicAdd(&cursor[r], 1);
  uint2 v;
  v.x = (unsigned)col[e];
  v.y = __float_as_uint(edge_w[e]);
  pw[row_ptr[r] + p] = v;
}

// ---------------- MFMA GEMM (bf16 inputs, f32 accumulate) ----------------
// Block tile (RT*32) x 128, 4 waves 2x2, wave tile (RT*16) x 64.
// A/B frags share the same lane->k map -> exact for any HW k-order.
// Epilogue: per-rt-stripe LDS transpose (per-wave buffer, 17.4 KB total)
// -> full-line vector stores.
// EPI: 0 = f32 C nt (adj)   1 = mu/z/logvar f32 nt + zbf bf16   2 = bf16 only
template <int KD, int RT, bool ABF, int EPI, bool SWZ>
__global__ __launch_bounds__(256) void mfma_gemm(
    const float* __restrict__ Af, const bf16_t* __restrict__ Abf,
    const bf16_t* __restrict__ BT, float* __restrict__ C, int ldc,
    float* __restrict__ dout, bf16_t* __restrict__ zbf, int ldz) {
  int bx, by;
  if constexpr (SWZ) {  // 4096 blocks over 64x64 tile grid: XCD-contiguous panels
    const int bid = blockIdx.x;
    const int s = (bid & 7) * 512 + (bid >> 3);
    by = s >> 6; bx = s & 63;
  } else {
    bx = blockIdx.x; by = blockIdx.y;
  }
  const int lane = threadIdx.x & 63;
  const int wid  = threadIdx.x >> 6;
  const int l15  = lane & 15;
  const int lg   = lane >> 4;
  const int brow = by * (RT * 32) + (wid >> 1) * (RT * 16);
  const int bcol = bx * 128 + (wid & 1) * 64;

  floatx4 acc[RT][4];
#pragma unroll
  for (int i = 0; i < RT; ++i)
#pragma unroll
    for (int j = 0; j < 4; ++j) acc[i][j] = (floatx4){0.f, 0.f, 0.f, 0.f};

#pragma unroll 1
  for (int kk = 0; kk < KD; kk += 32) {
    bf16x8 a[RT], b[4];
#pragma unroll
    for (int rt = 0; rt < RT; ++rt) {
      const int r = brow + rt * 16 + l15;
      if constexpr (ABF) {
        a[rt] = *(const bf16x8*)(Abf + (size_t)r * KD + kk + lg * 8);
      } else {
        const float* p = Af + (size_t)r * KD + kk + lg * 8;
        const floatx4 lo = *(const floatx4*)p;
        const floatx4 hi = *(const floatx4*)(p + 4);
        bf16x8 t;
        t[0] = (bf16_t)lo[0]; t[1] = (bf16_t)lo[1];
        t[2] = (bf16_t)lo[2]; t[3] = (bf16_t)lo[3];
        t[4] = (bf16_t)hi[0]; t[5] = (bf16_t)hi[1];
        t[6] = (bf16_t)hi[2]; t[7] = (bf16_t)hi[3];
        a[rt] = t;
      }
    }
#pragma unroll
    for (int ct = 0; ct < 4; ++ct) {
      const int c = bcol + ct * 16 + l15;
      b[ct] = *(const bf16x8*)(BT + (size_t)c * KD + kk + lg * 8);
    }
#pragma unroll
    for (int rt = 0; rt < RT; ++rt)
#pragma unroll
      for (int ct = 0; ct < 4; ++ct)
        acc[rt][ct] = __builtin_amdgcn_mfma_f32_16x16x32_bf16(
            a[rt], b[ct], acc[rt][ct], 0, 0, 0);
  }

  // ---- epilogue: per-rt 16x64 transpose through per-wave LDS ----
  __shared__ float lt[4][16 * 68];  // 17408 B total
  float* L = lt[wid];
#pragma unroll
  for (int rt = 0; rt < RT; ++rt) {
#pragma unroll
    for (int ct = 0; ct < 4; ++ct)
#pragma unroll
      for (int r = 0; r < 4; ++r)
        L[(lg * 4 + r) * 68 + ct * 16 + l15] = acc[rt][ct][r];
    __builtin_amdgcn_wave_barrier();
#pragma unroll
    for (int it = 0; it < 4; ++it) {
      const int idx = it * 64 + lane;
      const int rr = idx >> 4, c4 = idx & 15;
      const floatx4 v = *(const floatx4*)(L + rr * 68 + c4 * 4);
      const int orow = brow + rt * 16 + rr;
      const int gc = bcol + c4 * 4;
      if constexpr (EPI == 0) {
        __builtin_nontemporal_store(v, (floatx4*)(C + (size_t)orow * ldc + gc));
      } else if constexpr (EPI == 1) {
        if (gc < NH2) {
          __builtin_nontemporal_store(
              v, (floatx4*)(dout + OFF_MU + (size_t)orow * NH2 + gc));
          __builtin_nontemporal_store(
              v, (floatx4*)(dout + OFF_Z + (size_t)orow * NH2 + gc));
          bf16x4 o;
          o[0] = (bf16_t)v[0]; o[1] = (bf16_t)v[1];
          o[2] = (bf16_t)v[2]; o[3] = (bf16_t)v[3];
          *(bf16x4*)(zbf + (size_t)orow * ldz + gc) = o;
        } else {
          __builtin_nontemporal_store(
              v, (floatx4*)(dout + OFF_LOGVAR + (size_t)orow * NH2 + gc - NH2));
        }
      } else {
        bf16x4 o;
        o[0] = (bf16_t)v[0]; o[1] = (bf16_t)v[1];
        o[2] = (bf16_t)v[2]; o[3] = (bf16_t)v[3];
        *(bf16x4*)(zbf + (size_t)orow * ldz + gc) = o;
      }
    }
    __builtin_amdgcn_wave_barrier();
  }
}

// ---------------- SPMM bf16, d=256: one wave per row, 4 edges in flight ----------------
template <bool RELU>
__global__ __launch_bounds__(256) void spmm_b(
    const int* __restrict__ row_ptr, const uint2* __restrict__ pw,
    const bf16_t* __restrict__ src, float* __restrict__ dst_f,
    bf16_t* __restrict__ dst_b) {
  const int lane = threadIdx.x & 63;
  const int r = blockIdx.x * 4 + (threadIdx.x >> 6);
  const int li = lane & 15;  // channel group [li*16, li*16+16)
  const int g  = lane >> 4;  // edge slot 0..3
  const int beg = row_ptr[r];
  const int end = row_ptr[r + 1];
  float acc[16];
#pragma unroll
  for (int c = 0; c < 16; ++c) acc[c] = 0.f;

  for (int base = beg; base < end; base += 64) {
    const int t = base + lane;
    uint2 cw;
    cw.x = 0; cw.y = 0;
    if (t < end) cw = pw[t];
    const int cnt = min(64, end - base);
#pragma unroll 2
    for (int j4 = 0; j4 < cnt; j4 += 4) {
      const int cj = __shfl((int)cw.x, j4 + g);
      const float wj = __shfl(__uint_as_float(cw.y), j4 + g);
      const bf16_t* p = src + (size_t)cj * NH1 + li * 16;
      const bf16x8 v0 = *(const bf16x8*)p;
      const bf16x8 v1 = *(const bf16x8*)(p + 8);
#pragma unroll
      for (int c = 0; c < 8; ++c) {
        acc[c]     += wj * (float)v0[c];
        acc[8 + c] += wj * (float)v1[c];
      }
    }
  }
#pragma unroll
  for (int c = 0; c < 16; ++c) {
    acc[c] += __shfl_xor(acc[c], 16);
    acc[c] += __shfl_xor(acc[c], 32);
    if constexpr (RELU) acc[c] = fmaxf(acc[c], 0.f);
  }
  // static-index extraction of this lane's 4 channels (avoid scratch)
  float o0, o1, o2, o3;
  switch (g) {
    case 0:  o0 = acc[0];  o1 = acc[1];  o2 = acc[2];  o3 = acc[3];  break;
    case 1:  o0 = acc[4];  o1 = acc[5];  o2 = acc[6];  o3 = acc[7];  break;
    case 2:  o0 = acc[8];  o1 = acc[9];  o2 = acc[10]; o3 = acc[11]; break;
    default: o0 = acc[12]; o1 = acc[13]; o2 = acc[14]; o3 = acc[15]; break;
  }
  const int ch = li * 16 + g * 4;
  if (dst_f) {
    floatx4 o = (floatx4){o0, o1, o2, o3};
    __builtin_nontemporal_store(o, (floatx4*)(dst_f + (size_t)r * NH1 + ch));
  }
  if (dst_b) {
    bf16x4 o;
    o[0] = (bf16_t)o0; o[1] = (bf16_t)o1; o[2] = (bf16_t)o2; o[3] = (bf16_t)o3;
    *(bf16x4*)(dst_b + (size_t)r * NH1 + ch) = o;
  }
}

extern "C" void kernel_launch(void* const* d_in, const int* in_sizes, int n_in,
                              void* d_out, int out_size, void* d_ws, size_t ws_size,
                              hipStream_t stream) {
  const float* x      = (const float*)d_in[0];
  const float* W1     = (const float*)d_in[1];
  const float* W2     = (const float*)d_in[2];
  const float* W3     = (const float*)d_in[3];
  const float* edge_w = (const float*)d_in[4];
  const int*   row    = (const int*)d_in[5];
  const int*   col    = (const int*)d_in[6];
  float* out = (float*)d_out;
  char*  ws  = (char*)d_ws;

  bf16_t* XWb  = (bf16_t*)(ws);                         // 4 MB  [8192][256]
  bf16_t* h1b  = (bf16_t*)(ws + (4u << 20));            // 4 MB
  bf16_t* gb   = (bf16_t*)(ws + (8u << 20));            // 4 MB
  bf16_t* zbf  = (bf16_t*)(ws + (12u << 20));           // 2 MB  [8192][128]
  bf16_t* W1T  = (bf16_t*)(ws + (14u << 20));           // 256 KB
  bf16_t* W23T = (bf16_t*)(ws + (14u << 20) + (1u << 19));
  int* counts   = (int*)(ws + (15u << 20));
  int* cursor   = counts + NN;
  int* row_ptr  = cursor + NN;       // NN+1
  uint2* pw     = (uint2*)(ws + (15u << 20) + (1u << 18));  // 2 MB

  hipMemsetAsync(counts, 0, 2 * NN * sizeof(int), stream);
  prep_all<<<NE / 256, 256, 0, stream>>>(W1, W2, W3, row, W1T, W23T, counts);
  scan8k<<<1, 1024, 0, stream>>>(counts, row_ptr);
  edge_fill<<<NE / 256, 256, 0, stream>>>(row, col, edge_w, row_ptr, cursor, pw);

  // XWb = bf16(x @ W1)   [8192 x 256], 64x128 block tiles -> 256 blocks
  mfma_gemm<FIN, 2, false, 2, false><<<dim3(NH1 / 128, NN / 64), 256, 0, stream>>>(
      x, nullptr, W1T, nullptr, 0, nullptr, XWb, NH1);
  // h1 = relu(A . XWb) -> out (f32, nt) + h1b (bf16)
  spmm_b<true><<<NN / 4, 256, 0, stream>>>(row_ptr, pw, XWb, out + OFF_H1, h1b);
  // gb = bf16(A . h1b)
  spmm_b<false><<<NN / 4, 256, 0, stream>>>(row_ptr, pw, h1b, nullptr, gb);
  // [mu | logvar] = gb @ [W2 | W3]; writes mu/z/logvar f32 (nt) + zbf bf16
  mfma_gemm<NH1, 2, true, 1, false><<<dim3(NH1 / 128, NN / 64), 256, 0, stream>>>(
      nullptr, gb, W23T, nullptr, 0, out, zbf, NH2);
  // adj_rec = z @ z^T  [8192 x 8192], XCD-swizzled, transposed float4 nt stores
  mfma_gemm<NH2, 4, true, 0, true><<<4096, 256, 0, stream>>>(
      nullptr, zbf, zbf, out + OFF_ADJ, NN, nullptr, nullptr, 0);
}

// Round 7
// 141.205 us; speedup vs baseline: 6.6273x; 1.1224x over previous
//
#include <hip/hip_runtime.h>

typedef __bf16 bf16_t;
typedef __bf16 bf16x4 __attribute__((ext_vector_type(4)));
typedef __bf16 bf16x8 __attribute__((ext_vector_type(8)));
typedef float floatx4 __attribute__((ext_vector_type(4)));

static constexpr int NN  = 8192;
static constexpr int FIN = 512;
static constexpr int NH1 = 256;
static constexpr int NH2 = 128;
static constexpr int NE  = 262144;
static constexpr int CAP = 128;   // bucket capacity per row (mean deg 32, P(>128)~e^-70)

// output layout (floats): h1, adj_rec, mu, logvar, z
static constexpr size_t OFF_H1     = 0;
static constexpr size_t OFF_ADJ    = (size_t)NN * NH1;
static constexpr size_t OFF_MU     = OFF_ADJ + (size_t)NN * NN;
static constexpr size_t OFF_LOGVAR = OFF_MU + (size_t)NN * NH2;
static constexpr size_t OFF_Z      = OFF_LOGVAR + (size_t)NN * NH2;

// ---------------- GEMM body (bf16 MFMA, f32 acc) ----------------
// Block tile (RT*32) x 128, 4 waves 2x2, wave tile (RT*16) x 64.
// A/B frags share the same lane->k map -> exact for any HW k-order.
// Epilogue: per-rt 16x64 stripe transpose through per-wave LDS -> vector stores.
// EPI: 0 = f32 C nt (adj)   1 = mu/z/logvar f32 nt + zbf bf16   2 = bf16 only
template <int KD, int RT, bool ABF, int EPI>
__device__ __forceinline__ void gemm_body(
    int bx, int by, const float* __restrict__ Af, const bf16_t* __restrict__ Abf,
    const bf16_t* __restrict__ BT, float* __restrict__ C, int ldc,
    float* __restrict__ dout, bf16_t* __restrict__ zb, int ldz,
    float* __restrict__ L, int lane, int wid) {
  const int l15 = lane & 15;
  const int lg  = lane >> 4;
  const int brow = by * (RT * 32) + (wid >> 1) * (RT * 16);
  const int bcol = bx * 128 + (wid & 1) * 64;

  floatx4 acc[RT][4];
#pragma unroll
  for (int i = 0; i < RT; ++i)
#pragma unroll
    for (int j = 0; j < 4; ++j) acc[i][j] = (floatx4){0.f, 0.f, 0.f, 0.f};

#pragma unroll 1
  for (int kk = 0; kk < KD; kk += 32) {
    bf16x8 a[RT], b[4];
#pragma unroll
    for (int rt = 0; rt < RT; ++rt) {
      const int r = brow + rt * 16 + l15;
      if constexpr (ABF) {
        a[rt] = *(const bf16x8*)(Abf + (size_t)r * KD + kk + lg * 8);
      } else {
        const float* p = Af + (size_t)r * KD + kk + lg * 8;
        const floatx4 lo = *(const floatx4*)p;
        const floatx4 hi = *(const floatx4*)(p + 4);
        bf16x8 t;
        t[0] = (bf16_t)lo[0]; t[1] = (bf16_t)lo[1];
        t[2] = (bf16_t)lo[2]; t[3] = (bf16_t)lo[3];
        t[4] = (bf16_t)hi[0]; t[5] = (bf16_t)hi[1];
        t[6] = (bf16_t)hi[2]; t[7] = (bf16_t)hi[3];
        a[rt] = t;
      }
    }
#pragma unroll
    for (int ct = 0; ct < 4; ++ct) {
      const int c = bcol + ct * 16 + l15;
      b[ct] = *(const bf16x8*)(BT + (size_t)c * KD + kk + lg * 8);
    }
#pragma unroll
    for (int rt = 0; rt < RT; ++rt)
#pragma unroll
      for (int ct = 0; ct < 4; ++ct)
        acc[rt][ct] = __builtin_amdgcn_mfma_f32_16x16x32_bf16(
            a[rt], b[ct], acc[rt][ct], 0, 0, 0);
  }

#pragma unroll
  for (int rt = 0; rt < RT; ++rt) {
#pragma unroll
    for (int ct = 0; ct < 4; ++ct)
#pragma unroll
      for (int r = 0; r < 4; ++r)
        L[(lg * 4 + r) * 68 + ct * 16 + l15] = acc[rt][ct][r];
    __builtin_amdgcn_wave_barrier();
#pragma unroll
    for (int it = 0; it < 4; ++it) {
      const int idx = it * 64 + lane;
      const int rr = idx >> 4, c4 = idx & 15;
      const floatx4 v = *(const floatx4*)(L + rr * 68 + c4 * 4);
      const int orow = brow + rt * 16 + rr;
      const int gc = bcol + c4 * 4;
      if constexpr (EPI == 0) {
        __builtin_nontemporal_store(v, (floatx4*)(C + (size_t)orow * ldc + gc));
      } else if constexpr (EPI == 1) {
        if (gc < NH2) {
          __builtin_nontemporal_store(
              v, (floatx4*)(dout + OFF_MU + (size_t)orow * NH2 + gc));
          __builtin_nontemporal_store(
              v, (floatx4*)(dout + OFF_Z + (size_t)orow * NH2 + gc));
          bf16x4 o;
          o[0] = (bf16_t)v[0]; o[1] = (bf16_t)v[1];
          o[2] = (bf16_t)v[2]; o[3] = (bf16_t)v[3];
          *(bf16x4*)(zb + (size_t)orow * ldz + gc) = o;
        } else {
          __builtin_nontemporal_store(
              v, (floatx4*)(dout + OFF_LOGVAR + (size_t)orow * NH2 + gc - NH2));
        }
      } else {
        bf16x4 o;
        o[0] = (bf16_t)v[0]; o[1] = (bf16_t)v[1];
        o[2] = (bf16_t)v[2]; o[3] = (bf16_t)v[3];
        *(bf16x4*)(zb + (size_t)orow * ldz + gc) = o;
      }
    }
    __builtin_amdgcn_wave_barrier();
  }
}

// ---------------- K0: zero counts/spill + weight transpose to bf16 ----------------
__global__ __launch_bounds__(256) void k_prep(
    const float* __restrict__ W1, const float* __restrict__ W2,
    const float* __restrict__ W3, bf16_t* __restrict__ W1T,
    bf16_t* __restrict__ W23T, int* __restrict__ counts) {
  const int gid = blockIdx.x * 256 + threadIdx.x;  // grid 512 -> 131072 threads
  if (gid <= NN) counts[gid] = 0;                  // counts[NN] = spill counter
  if (gid < NH1 * FIN) {
    const int n = gid >> 9, k = gid & 511;
    W1T[gid] = (bf16_t)W1[k * NH1 + n];
  }
  if (gid < NH1 * NH1) {
    const int n = gid >> 8, k = gid & 255;
    W23T[gid] = (bf16_t)(n < NH2 ? W2[k * NH2 + n] : W3[k * NH2 + (n - NH2)]);
  }
}

// ---------------- K1 fat: gemm1 (blocks 0..255) || bucket fill (256..1279) ----------------
__global__ __launch_bounds__(256) void k_fat(
    const float* __restrict__ x, const bf16_t* __restrict__ W1T,
    bf16_t* __restrict__ XWb, const int* __restrict__ row,
    const int* __restrict__ col, const float* __restrict__ edge_w,
    int* __restrict__ counts, uint2* __restrict__ bucket,
    uint4* __restrict__ spill) {
  __shared__ float lt[4][16 * 68];
  const int bid = blockIdx.x;
  if (bid < 256) {
    const int lane = threadIdx.x & 63;
    const int wid  = threadIdx.x >> 6;
    gemm_body<FIN, 2, false, 2>(bid & 1, bid >> 1, x, nullptr, W1T, nullptr, 0,
                                nullptr, XWb, NH1, lt[wid], lane, wid);
  } else {
    const int e = (bid - 256) * 256 + threadIdx.x;  // 1024*256 == NE
    const int r = row[e];
    const int p = atomicAdd(&counts[r], 1);
    if (p < CAP) {
      uint2 v;
      v.x = (unsigned)col[e];
      v.y = __float_as_uint(edge_w[e]);
      bucket[(size_t)r * CAP + p] = v;
    } else {  // never in practice; correctness fallback
      const int s = atomicAdd(&counts[NN], 1);
      uint4 v;
      v.x = (unsigned)r; v.y = (unsigned)col[e];
      v.z = __float_as_uint(edge_w[e]); v.w = 0;
      spill[s] = v;
    }
  }
}

// ---------------- SPMM from buckets, d=256: one wave per row ----------------
template <bool RELU>
__global__ __launch_bounds__(256) void spmm_bucket(
    const int* __restrict__ counts, const uint2* __restrict__ bucket,
    const uint4* __restrict__ spill, const bf16_t* __restrict__ src,
    float* __restrict__ dst_f, bf16_t* __restrict__ dst_b) {
  const int lane = threadIdx.x & 63;
  const int r = blockIdx.x * 4 + (threadIdx.x >> 6);
  const int li = lane & 15;  // channel group [li*16, li*16+16)
  const int g  = lane >> 4;  // edge slot 0..3
  const int deg = min(counts[r], CAP);
  float acc[16];
#pragma unroll
  for (int c = 0; c < 16; ++c) acc[c] = 0.f;

  for (int base = 0; base < deg; base += 64) {
    const int t = base + lane;
    uint2 cw;
    cw.x = 0; cw.y = 0;
    if (t < deg) cw = bucket[(size_t)r * CAP + t];
    const int cnt = min(64, deg - base);
#pragma unroll 2
    for (int j4 = 0; j4 < cnt; j4 += 4) {
      const int cj = __shfl((int)cw.x, j4 + g);
      const float wj = __shfl(__uint_as_float(cw.y), j4 + g);
      const bf16_t* p = src + (size_t)cj * NH1 + li * 16;
      const bf16x8 v0 = *(const bf16x8*)p;
      const bf16x8 v1 = *(const bf16x8*)(p + 8);
#pragma unroll
      for (int c = 0; c < 8; ++c) {
        acc[c]     += wj * (float)v0[c];
        acc[8 + c] += wj * (float)v1[c];
      }
    }
  }
  // spill fallback (counts[NN]==0 in practice; one cached load)
  const int ns = counts[NN];
  if (ns > 0 && g == 0) {
    for (int i = 0; i < ns; ++i) {
      const uint4 s = spill[i];
      if ((int)s.x == r) {
        const float wj = __uint_as_float(s.z);
        const bf16_t* p = src + (size_t)s.y * NH1 + li * 16;
        const bf16x8 v0 = *(const bf16x8*)p;
        const bf16x8 v1 = *(const bf16x8*)(p + 8);
#pragma unroll
        for (int c = 0; c < 8; ++c) {
          acc[c]     += wj * (float)v0[c];
          acc[8 + c] += wj * (float)v1[c];
        }
      }
    }
  }
#pragma unroll
  for (int c = 0; c < 16; ++c) {
    acc[c] += __shfl_xor(acc[c], 16);
    acc[c] += __shfl_xor(acc[c], 32);
    if constexpr (RELU) acc[c] = fmaxf(acc[c], 0.f);
  }
  float o0, o1, o2, o3;
  switch (g) {
    case 0:  o0 = acc[0];  o1 = acc[1];  o2 = acc[2];  o3 = acc[3];  break;
    case 1:  o0 = acc[4];  o1 = acc[5];  o2 = acc[6];  o3 = acc[7];  break;
    case 2:  o0 = acc[8];  o1 = acc[9];  o2 = acc[10]; o3 = acc[11]; break;
    default: o0 = acc[12]; o1 = acc[13]; o2 = acc[14]; o3 = acc[15]; break;
  }
  const int ch = li * 16 + g * 4;
  if (dst_f) {
    floatx4 o = (floatx4){o0, o1, o2, o3};
    __builtin_nontemporal_store(o, (floatx4*)(dst_f + (size_t)r * NH1 + ch));
  }
  if (dst_b) {
    bf16x4 o;
    o[0] = (bf16_t)o0; o[1] = (bf16_t)o1; o[2] = (bf16_t)o2; o[3] = (bf16_t)o3;
    *(bf16x4*)(dst_b + (size_t)r * NH1 + ch) = o;
  }
}

// ---------------- standalone GEMM wrappers ----------------
template <int KD, int RT, bool ABF, int EPI, bool SWZ>
__global__ __launch_bounds__(256) void mfma_gemm(
    const float* __restrict__ Af, const bf16_t* __restrict__ Abf,
    const bf16_t* __restrict__ BT, float* __restrict__ C, int ldc,
    float* __restrict__ dout, bf16_t* __restrict__ zb, int ldz) {
  __shared__ float lt[4][16 * 68];
  int bx, by;
  if constexpr (SWZ) {  // 4096 blocks over 64x64 tiles of 128x128: XCD panels
    const int bid = blockIdx.x;
    const int s = (bid & 7) * 512 + (bid >> 3);
    by = s >> 6; bx = s & 63;
  } else {
    bx = blockIdx.x; by = blockIdx.y;
  }
  const int lane = threadIdx.x & 63;
  const int wid  = threadIdx.x >> 6;
  gemm_body<KD, RT, ABF, EPI>(bx, by, Af, Abf, BT, C, ldc, dout, zb, ldz,
                              lt[wid], lane, wid);
}

extern "C" void kernel_launch(void* const* d_in, const int* in_sizes, int n_in,
                              void* d_out, int out_size, void* d_ws, size_t ws_size,
                              hipStream_t stream) {
  const float* x      = (const float*)d_in[0];
  const float* W1     = (const float*)d_in[1];
  const float* W2     = (const float*)d_in[2];
  const float* W3     = (const float*)d_in[3];
  const float* edge_w = (const float*)d_in[4];
  const int*   row    = (const int*)d_in[5];
  const int*   col    = (const int*)d_in[6];
  float* out = (float*)d_out;
  char*  ws  = (char*)d_ws;

  // ws layout (~17.1 MB), with overlays: gb reuses XWb, zbf reuses h1b
  bf16_t* XWb  = (bf16_t*)(ws);                          // 4 MB; later gb
  bf16_t* h1b  = (bf16_t*)(ws + (4u << 20));             // 4 MB; later zbf
  bf16_t* W1T  = (bf16_t*)(ws + (8u << 20));             // 256 KB
  bf16_t* W23T = (bf16_t*)(ws + (8u << 20) + (1u << 18));// 128 KB
  int*    counts = (int*)(ws + (8u << 20) + (3u << 18)); // (NN+1)*4B
  uint2*  bucket = (uint2*)(ws + (9u << 20));            // 8 MB
  uint4*  spill  = (uint4*)(ws + (17u << 20));           // 64 KB
  bf16_t* gb  = XWb;
  bf16_t* zbf = h1b;

  // K0: zero counts + weight transpose
  k_prep<<<512, 256, 0, stream>>>(W1, W2, W3, W1T, W23T, counts);
  // K1: gemm1 (XWb = bf16(x@W1)) || bucket fill
  k_fat<<<1280, 256, 0, stream>>>(x, W1T, XWb, row, col, edge_w, counts, bucket,
                                  spill);
  // K2: h1 = relu(A . XWb) -> out f32 (nt) + h1b
  spmm_bucket<true><<<NN / 4, 256, 0, stream>>>(counts, bucket, spill, XWb,
                                                out + OFF_H1, h1b);
  // K3: gb = bf16(A . h1b)   (gb overlays XWb, which is dead now)
  spmm_bucket<false><<<NN / 4, 256, 0, stream>>>(counts, bucket, spill, h1b,
                                                 nullptr, gb);
  // K4: [mu|logvar] = gb @ [W2|W3] -> mu/z/logvar f32 (nt) + zbf (overlays h1b)
  mfma_gemm<NH1, 2, true, 1, false><<<dim3(2, 128), 256, 0, stream>>>(
      nullptr, gb, W23T, nullptr, 0, out, zbf, NH2);
  // K5: adj = z @ z^T, XCD-swizzled, transposed float4 nt stores
  mfma_gemm<NH2, 4, true, 0, true><<<4096, 256, 0, stream>>>(
      nullptr, zbf, zbf, out + OFF_ADJ, NN, nullptr, nullptr, 0);
}